// Round 10
// baseline (225.005 us; speedup 1.0000x reference)
//
#include <hip/hip_runtime.h>
#include <hip/hip_fp16.h>
#include <hip/hip_cooperative_groups.h>
#include <math.h>

namespace cg = cooperative_groups;

// Problem constants
constexpr int D     = 64;
constexpr int H     = 14;
constexpr int HP2   = 8;     // half2 stride per node row (32B)
constexpr int P     = 16;
constexpr int LATc  = 7;
constexpr int OUTW  = 30;
constexpr float SP_INV_1 = 0.5413248546129181f;

constexpr int BLK = 256;

// Packed fp16 atomic add (memory-side RMW; header overload missing in ROCm 7.2)
__device__ __forceinline__ void pk_atomic_add_f16(__half2* addr, __half2 val) {
    unsigned int bits = *reinterpret_cast<unsigned int*>(&val);
    asm volatile("global_atomic_pk_add_f16 %0, %1, off"
                 :: "v"(addr), "v"(bits) : "memory");
}
// Agent(device)-scope store/load: write-through / bypass stale per-XCD L2
__device__ __forceinline__ void st_agent(unsigned int* p, unsigned int v) {
    __hip_atomic_store(p, v, __ATOMIC_RELAXED, __HIP_MEMORY_SCOPE_AGENT);
}
__device__ __forceinline__ unsigned int ld_agent(const unsigned int* p) {
    return __hip_atomic_load(p, __ATOMIC_RELAXED, __HIP_MEMORY_SCOPE_AGENT);
}

// ===================== Cooperative mega-kernel ==============================
__global__ __launch_bounds__(BLK) void mega_kernel(
        const float* __restrict__ X,
        const int* __restrict__ rows,
        const int* __restrict__ cols,
        const float* __restrict__ vals,
        const float* __restrict__ W1,
        const float* __restrict__ W2,
        const float* __restrict__ Wd1,
        const float* __restrict__ bd1,
        const float* __restrict__ Wd2,
        const float* __restrict__ bd2,
        float* __restrict__ out,
        unsigned int* __restrict__ XWu,
        unsigned int* __restrict__ HWu,
        unsigned int* __restrict__ Y1u,
        unsigned int* __restrict__ Y2u,
        int N, int E) {
    cg::grid_group grid = cg::this_grid();

    __shared__ float w1[D * H], w2[H * H], wd1[H * H], wd2[H * P], sb1[H], sb2[P];
    for (int i = threadIdx.x; i < D * H; i += BLK) w1[i] = W1[i];
    for (int i = threadIdx.x; i < H * H; i += BLK) { w2[i] = W2[i]; wd1[i] = Wd1[i]; }
    for (int i = threadIdx.x; i < H * P; i += BLK) wd2[i] = Wd2[i];
    if (threadIdx.x < H) sb1[threadIdx.x] = bd1[threadIdx.x];
    if (threadIdx.x < P) sb2[threadIdx.x] = bd2[threadIdx.x];
    __syncthreads();

    const int tid = blockIdx.x * BLK + threadIdx.x;
    const int nth = gridDim.x * BLK;

    // ---- P0: XW = fp16(X @ W1) + zero Y1/Y2 (agent stores) -----------------
    for (int n = tid; n < N; n += nth) {
        float acc[H];
#pragma unroll
        for (int j = 0; j < H; ++j) acc[j] = 0.f;
        const float4* xr = reinterpret_cast<const float4*>(X + (size_t)n * D);
#pragma unroll
        for (int d4 = 0; d4 < D / 4; ++d4) {
            float4 x = xr[d4];
            float xs[4] = {x.x, x.y, x.z, x.w};
#pragma unroll
            for (int k = 0; k < 4; ++k) {
                int d = d4 * 4 + k;
#pragma unroll
                for (int j = 0; j < H; ++j) acc[j] = fmaf(xs[k], w1[d * H + j], acc[j]);
            }
        }
        unsigned int* xw = XWu + (size_t)n * HP2;
#pragma unroll
        for (int j = 0; j < 7; ++j) {
            __half2 hv = __floats2half2_rn(acc[2 * j], acc[2 * j + 1]);
            st_agent(&xw[j], *reinterpret_cast<unsigned int*>(&hv));
        }
        st_agent(&xw[7], 0u);
        unsigned int* y1 = Y1u + (size_t)n * HP2;
        unsigned int* y2 = Y2u + (size_t)n * HP2;
#pragma unroll
        for (int j = 0; j < HP2; ++j) { st_agent(&y1[j], 0u); st_agent(&y2[j], 0u); }
    }
    __threadfence();
    grid.sync();

    // ---- P1: spmm1: Y1 += vals * XW[cols] (pk-f16 atomics) -----------------
    {
        const __half2* F = reinterpret_cast<const __half2*>(XWu);
        __half2* Y = reinterpret_cast<__half2*>(Y1u);
        long long tot = (long long)E * 8;
        for (long long i = tid; i < tot; i += nth) {
            int e = (int)(i >> 3), f = (int)(i & 7);
            if (f < 7) {
                int r = rows[e], c = cols[e];
                float v = vals[e];
                float2 xf = __half22float2(F[c * HP2 + f]);
                __half2 p = __floats2half2_rn(v * xf.x, v * xf.y);
                pk_atomic_add_f16(&Y[r * HP2 + f], p);
            }
        }
    }
    __threadfence();
    grid.sync();

    // ---- P2: HW = fp16(relu(Y1) @ W2) --------------------------------------
    for (int n = tid; n < N; n += nth) {
        const unsigned int* y1 = Y1u + (size_t)n * HP2;
        float h[H];
#pragma unroll
        for (int k = 0; k < 7; ++k) {
            unsigned int u = ld_agent(&y1[k]);
            float2 t = __half22float2(*reinterpret_cast<__half2*>(&u));
            h[2 * k] = fmaxf(t.x, 0.f);
            h[2 * k + 1] = fmaxf(t.y, 0.f);
        }
        unsigned int* hw = HWu + (size_t)n * HP2;
#pragma unroll
        for (int j = 0; j < 7; ++j) {
            float a0 = 0.f, a1 = 0.f;
#pragma unroll
            for (int i = 0; i < H; ++i) {
                a0 = fmaf(h[i], w2[i * H + 2 * j], a0);
                a1 = fmaf(h[i], w2[i * H + 2 * j + 1], a1);
            }
            __half2 hv = __floats2half2_rn(a0, a1);
            st_agent(&hw[j], *reinterpret_cast<unsigned int*>(&hv));
        }
        st_agent(&hw[7], 0u);
    }
    __threadfence();
    grid.sync();

    // ---- P3: spmm2: Y2 += vals * HW[cols] ----------------------------------
    {
        const __half2* F = reinterpret_cast<const __half2*>(HWu);
        __half2* Y = reinterpret_cast<__half2*>(Y2u);
        long long tot = (long long)E * 8;
        for (long long i = tid; i < tot; i += nth) {
            int e = (int)(i >> 3), f = (int)(i & 7);
            if (f < 7) {
                int r = rows[e], c = cols[e];
                float v = vals[e];
                float2 xf = __half22float2(F[c * HP2 + f]);
                __half2 p = __floats2half2_rn(v * xf.x, v * xf.y);
                pk_atomic_add_f16(&Y[r * HP2 + f], p);
            }
        }
    }
    __threadfence();
    grid.sync();

    // ---- P4: heads -> out ---------------------------------------------------
    for (int n = tid; n < N; n += nth) {
        const unsigned int* y2 = Y2u + (size_t)n * HP2;
        float h[H];
#pragma unroll
        for (int k = 0; k < 7; ++k) {
            unsigned int u = ld_agent(&y2[k]);
            float2 t = __half22float2(*reinterpret_cast<__half2*>(&u));
            h[2 * k] = fmaxf(t.x, 0.f);
            h[2 * k + 1] = fmaxf(t.y, 0.f);
        }
        float pd[H];
#pragma unroll
        for (int j = 0; j < H; ++j) {
            float a = sb1[j];
#pragma unroll
            for (int i = 0; i < H; ++i) a = fmaf(h[i], wd1[i * H + j], a);
            pd[j] = tanhf(a);
        }
        float pp[P];
#pragma unroll
        for (int j = 0; j < P; ++j) {
            float a = sb2[j];
#pragma unroll
            for (int i = 0; i < H; ++i) a = fmaf(h[i], wd2[i * P + j], a);
            pp[j] = tanhf(a);
        }
        float* o = out + (size_t)n * OUTW;
#pragma unroll
        for (int k = 0; k < LATc; ++k) o[k] = pd[k];
#pragma unroll
        for (int k = 0; k < LATc; ++k) {
            float x = pd[LATc + k] + SP_INV_1;
            o[LATc + k] = log1pf(expf(x));
        }
#pragma unroll
        for (int k = 0; k < H; ++k) o[14 + k] = pp[k];
        o[28] = pp[14];
        o[29] = pp[15];
    }
}

// ===================== Fallback: proven R7 5-kernel path ====================
__global__ void dense_xw_kernel(const float* __restrict__ X,
                                const float* __restrict__ W1,
                                __half2* __restrict__ XW, int N) {
    __shared__ float w[D * H];
    for (int i = threadIdx.x; i < D * H; i += blockDim.x) w[i] = W1[i];
    __syncthreads();
    int n = blockIdx.x * blockDim.x + threadIdx.x;
    if (n >= N) return;
    float acc[H];
#pragma unroll
    for (int j = 0; j < H; ++j) acc[j] = 0.f;
    const float4* xr = reinterpret_cast<const float4*>(X + (size_t)n * D);
#pragma unroll
    for (int d4 = 0; d4 < D / 4; ++d4) {
        float4 x = xr[d4];
        float xs[4] = {x.x, x.y, x.z, x.w};
#pragma unroll
        for (int k = 0; k < 4; ++k) {
            int d = d4 * 4 + k;
#pragma unroll
            for (int j = 0; j < H; ++j) acc[j] = fmaf(xs[k], w[d * H + j], acc[j]);
        }
    }
    __half2 ov[HP2];
#pragma unroll
    for (int j = 0; j < 7; ++j) ov[j] = __floats2half2_rn(acc[2 * j], acc[2 * j + 1]);
    ov[7] = __floats2half2_rn(0.f, 0.f);
    float4* dst = reinterpret_cast<float4*>(XW + (size_t)n * HP2);
    dst[0] = *reinterpret_cast<float4*>(&ov[0]);
    dst[1] = *reinterpret_cast<float4*>(&ov[4]);
}

__global__ void spmm_pk_kernel(const __half2* __restrict__ F,
                               const int* __restrict__ rows,
                               const int* __restrict__ cols,
                               const float* __restrict__ vals,
                               __half2* __restrict__ Y, int E) {
    int idx = blockIdx.x * blockDim.x + threadIdx.x;
    int e = idx >> 3;
    int f = idx & 7;
    if (e >= E || f >= 7) return;
    int r = rows[e];
    int c = cols[e];
    float v = vals[e];
    float2 xf = __half22float2(F[c * HP2 + f]);
    __half2 p = __floats2half2_rn(v * xf.x, v * xf.y);
    pk_atomic_add_f16(&Y[r * HP2 + f], p);
}

__global__ void dense_hw_kernel(const __half2* __restrict__ Y1,
                                const float* __restrict__ W2,
                                __half2* __restrict__ HW, int N) {
    __shared__ float w[H * H];
    for (int i = threadIdx.x; i < H * H; i += blockDim.x) w[i] = W2[i];
    __syncthreads();
    int n = blockIdx.x * blockDim.x + threadIdx.x;
    if (n >= N) return;
    const float4* yr4 = reinterpret_cast<const float4*>(Y1 + (size_t)n * HP2);
    float4 ya = yr4[0], yb = yr4[1];
    __half2 yh[HP2];
    *reinterpret_cast<float4*>(&yh[0]) = ya;
    *reinterpret_cast<float4*>(&yh[4]) = yb;
    float h[H];
#pragma unroll
    for (int k = 0; k < 7; ++k) {
        float2 t = __half22float2(yh[k]);
        h[2 * k]     = fmaxf(t.x, 0.f);
        h[2 * k + 1] = fmaxf(t.y, 0.f);
    }
    float o[H];
#pragma unroll
    for (int j = 0; j < H; ++j) {
        float a = 0.f;
#pragma unroll
        for (int i = 0; i < H; ++i) a = fmaf(h[i], w[i * H + j], a);
        o[j] = a;
    }
    __half2 ov[HP2];
#pragma unroll
    for (int j = 0; j < 7; ++j) ov[j] = __floats2half2_rn(o[2 * j], o[2 * j + 1]);
    ov[7] = __floats2half2_rn(0.f, 0.f);
    float4* dst = reinterpret_cast<float4*>(HW + (size_t)n * HP2);
    dst[0] = *reinterpret_cast<float4*>(&ov[0]);
    dst[1] = *reinterpret_cast<float4*>(&ov[4]);
}

__global__ void final_kernel(const __half2* __restrict__ Y2,
                             const float* __restrict__ Wd1,
                             const float* __restrict__ bd1,
                             const float* __restrict__ Wd2,
                             const float* __restrict__ bd2,
                             float* __restrict__ out, int N) {
    __shared__ float wd1[H * H], wd2[H * P], b1[H], b2[P];
    for (int i = threadIdx.x; i < H * H; i += blockDim.x) wd1[i] = Wd1[i];
    for (int i = threadIdx.x; i < H * P; i += blockDim.x) wd2[i] = Wd2[i];
    if (threadIdx.x < H) b1[threadIdx.x] = bd1[threadIdx.x];
    if (threadIdx.x < P) b2[threadIdx.x] = bd2[threadIdx.x];
    __syncthreads();
    int n = blockIdx.x * blockDim.x + threadIdx.x;
    if (n >= N) return;

    const float4* yr4 = reinterpret_cast<const float4*>(Y2 + (size_t)n * HP2);
    float4 ya = yr4[0], yb = yr4[1];
    __half2 yh[HP2];
    *reinterpret_cast<float4*>(&yh[0]) = ya;
    *reinterpret_cast<float4*>(&yh[4]) = yb;
    float h[H];
#pragma unroll
    for (int k = 0; k < 7; ++k) {
        float2 t = __half22float2(yh[k]);
        h[2 * k]     = fmaxf(t.x, 0.f);
        h[2 * k + 1] = fmaxf(t.y, 0.f);
    }

    float pd[H];
#pragma unroll
    for (int j = 0; j < H; ++j) {
        float a = b1[j];
#pragma unroll
        for (int i = 0; i < H; ++i) a = fmaf(h[i], wd1[i * H + j], a);
        pd[j] = tanhf(a);
    }
    float pp[P];
#pragma unroll
    for (int j = 0; j < P; ++j) {
        float a = b2[j];
#pragma unroll
        for (int i = 0; i < H; ++i) a = fmaf(h[i], wd2[i * P + j], a);
        pp[j] = tanhf(a);
    }

    float* o = out + (size_t)n * OUTW;
#pragma unroll
    for (int k = 0; k < LATc; ++k) o[k] = pd[k];
#pragma unroll
    for (int k = 0; k < LATc; ++k) {
        float x = pd[LATc + k] + SP_INV_1;
        o[LATc + k] = log1pf(expf(x));
    }
#pragma unroll
    for (int k = 0; k < H; ++k) o[14 + k] = pp[k];
    o[28] = pp[14];
    o[29] = pp[15];
}

extern "C" void kernel_launch(void* const* d_in, const int* in_sizes, int n_in,
                              void* d_out, int out_size, void* d_ws, size_t ws_size,
                              hipStream_t stream) {
    const float* X    = (const float*)d_in[0];
    const int*   rows = (const int*)d_in[1];
    const int*   cols = (const int*)d_in[2];
    const float* vals = (const float*)d_in[3];
    const float* W1   = (const float*)d_in[4];
    const float* W2   = (const float*)d_in[5];
    const float* Wd1  = (const float*)d_in[6];
    const float* bd1  = (const float*)d_in[7];
    const float* Wd2  = (const float*)d_in[8];
    const float* bd2  = (const float*)d_in[9];
    float* out = (float*)d_out;

    int N = in_sizes[0] / D;   // 100000
    int E = in_sizes[1];       // 1000000

    unsigned int* XWu = (unsigned int*)d_ws;
    unsigned int* HWu = XWu + (size_t)N * HP2;
    unsigned int* Y1u = HWu + (size_t)N * HP2;
    unsigned int* Y2u = Y1u + (size_t)N * HP2;

    // Size the cooperative grid from measured occupancy (host-side queries,
    // deterministic every call -> graph-capture safe).
    int blocksPerCU = 0;
    hipError_t qerr = hipOccupancyMaxActiveBlocksPerMultiprocessor(
        &blocksPerCU, (const void*)mega_kernel, BLK, 0);
    int numCU = 0;
    hipError_t aerr = hipDeviceGetAttribute(&numCU,
        hipDeviceAttributeMultiprocessorCount, 0);

    bool coop_ok = (qerr == hipSuccess && aerr == hipSuccess && blocksPerCU > 0 && numCU > 0);
    if (coop_ok) {
        int grid = blocksPerCU * numCU;
        if (grid > 2048) grid = 2048;
        void* args[] = {&X, &rows, &cols, &vals, &W1, &W2, &Wd1, &bd1, &Wd2, &bd2,
                        &out, &XWu, &HWu, &Y1u, &Y2u, &N, &E};
        hipError_t lerr = hipLaunchCooperativeKernel((const void*)mega_kernel,
                                                     dim3(grid), dim3(BLK),
                                                     args, 0, stream);
        if (lerr == hipSuccess) return;
    }

    // -------- Fallback: proven 5-kernel pipeline (221.5 us) -----------------
    __half2* XW = (__half2*)XWu;
    __half2* HW = (__half2*)HWu;
    __half2* Y1 = (__half2*)Y1u;
    __half2* Y2 = (__half2*)Y2u;

    (void)hipMemsetAsync(Y1, 0, (size_t)N * HP2 * 2 * sizeof(__half2), stream);

    int blkN = (N + 255) / 256;
    long long spmmThreads = (long long)E * 8;
    unsigned blkS = (unsigned)((spmmThreads + 255) / 256);

    dense_xw_kernel<<<blkN, 256, 0, stream>>>(X, W1, XW, N);
    spmm_pk_kernel<<<blkS, 256, 0, stream>>>(XW, rows, cols, vals, Y1, E);
    dense_hw_kernel<<<blkN, 256, 0, stream>>>(Y1, W2, HW, N);
    spmm_pk_kernel<<<blkS, 256, 0, stream>>>(HW, rows, cols, vals, Y2, E);
    final_kernel<<<blkN, 256, 0, stream>>>(Y2, Wd1, bd1, Wd2, bd2, out, N);
}

// Round 11
// 219.036 us; speedup vs baseline: 1.0273x; 1.0273x over previous
//
#include <hip/hip_runtime.h>
#include <hip/hip_fp16.h>
#include <math.h>

// Problem constants
constexpr int D     = 64;
constexpr int H     = 14;
constexpr int HP2   = 8;     // half2 stride per node row (32B)
constexpr int P     = 16;
constexpr int LATc  = 7;
constexpr int OUTW  = 30;
constexpr float SP_INV_1 = 0.5413248546129181f;

// Packed fp16 atomic add (memory-side RMW; header overload missing in ROCm 7.2)
__device__ __forceinline__ void pk_atomic_add_f16(__half2* addr, __half2 val) {
    unsigned int bits = *reinterpret_cast<unsigned int*>(&val);
    asm volatile("global_atomic_pk_add_f16 %0, %1, off"
                 :: "v"(addr), "v"(bits) : "memory");
}

// ---------------- Dense: XW = fp16(X @ W1); also zeroes Y1/Y2 --------------
// 2 threads per node: thread half=h accumulates all 14 features over
// d in [32h, 32h+32), pair-reduce via shfl_xor(1), each stores 16B.
__global__ void dense_xw_kernel(const float* __restrict__ X,
                                const float* __restrict__ W1,
                                __half2* __restrict__ XW,
                                __half2* __restrict__ Y1,
                                __half2* __restrict__ Y2, int N) {
    __shared__ float w[D * H];
    for (int i = threadIdx.x; i < D * H; i += blockDim.x) w[i] = W1[i];
    __syncthreads();
    int t = blockIdx.x * blockDim.x + threadIdx.x;
    int n = t >> 1;
    int half = t & 1;
    if (n >= N) return;

    float acc[H];
#pragma unroll
    for (int j = 0; j < H; ++j) acc[j] = 0.f;
    const float4* xr = reinterpret_cast<const float4*>(X + (size_t)n * D) + half * 8;
#pragma unroll
    for (int d4 = 0; d4 < 8; ++d4) {
        float4 x = xr[d4];
        float xs[4] = {x.x, x.y, x.z, x.w};
#pragma unroll
        for (int k = 0; k < 4; ++k) {
            int d = half * 32 + d4 * 4 + k;
#pragma unroll
            for (int j = 0; j < H; ++j) acc[j] = fmaf(xs[k], w[d * H + j], acc[j]);
        }
    }
    // pair-reduce: lanes 2n, 2n+1 are adjacent in the same wave
#pragma unroll
    for (int j = 0; j < H; ++j) acc[j] += __shfl_xor(acc[j], 1);

    // half=0 stores features 0..7, half=1 stores 8..13 + pad (16B each)
    __half2 ov[4];
    if (half == 0) {
        ov[0] = __floats2half2_rn(acc[0], acc[1]);
        ov[1] = __floats2half2_rn(acc[2], acc[3]);
        ov[2] = __floats2half2_rn(acc[4], acc[5]);
        ov[3] = __floats2half2_rn(acc[6], acc[7]);
    } else {
        ov[0] = __floats2half2_rn(acc[8], acc[9]);
        ov[1] = __floats2half2_rn(acc[10], acc[11]);
        ov[2] = __floats2half2_rn(acc[12], acc[13]);
        ov[3] = __floats2half2_rn(0.f, 0.f);
    }
    reinterpret_cast<float4*>(XW + (size_t)n * HP2)[half] = *reinterpret_cast<float4*>(ov);

    // zero the atomic accumulators (replaces hipMemsetAsync dispatch)
    float4 z = make_float4(0.f, 0.f, 0.f, 0.f);
    reinterpret_cast<float4*>(Y1 + (size_t)n * HP2)[half] = z;
    reinterpret_cast<float4*>(Y2 + (size_t)n * HP2)[half] = z;
}

// ---------------- SpMM with packed-fp16 atomics (proven 51.5us) ------------
__global__ void spmm_pk_kernel(const __half2* __restrict__ F,
                               const int* __restrict__ rows,
                               const int* __restrict__ cols,
                               const float* __restrict__ vals,
                               __half2* __restrict__ Y, int E) {
    int idx = blockIdx.x * blockDim.x + threadIdx.x;
    int e = idx >> 3;
    int f = idx & 7;
    if (e >= E || f >= 7) return;
    int r = rows[e];
    int c = cols[e];
    float v = vals[e];
    float2 xf = __half22float2(F[c * HP2 + f]);
    __half2 p = __floats2half2_rn(v * xf.x, v * xf.y);
    pk_atomic_add_f16(&Y[r * HP2 + f], p);
}

// ---------------- Dense: HW = fp16(relu(Y1) @ W2) --------------------------
__global__ void dense_hw_kernel(const __half2* __restrict__ Y1,
                                const float* __restrict__ W2,
                                __half2* __restrict__ HW, int N) {
    __shared__ float w[H * H];
    for (int i = threadIdx.x; i < H * H; i += blockDim.x) w[i] = W2[i];
    __syncthreads();
    int n = blockIdx.x * blockDim.x + threadIdx.x;
    if (n >= N) return;
    const float4* yr4 = reinterpret_cast<const float4*>(Y1 + (size_t)n * HP2);
    float4 ya = yr4[0], yb = yr4[1];
    __half2 yh[HP2];
    *reinterpret_cast<float4*>(&yh[0]) = ya;
    *reinterpret_cast<float4*>(&yh[4]) = yb;
    float h[H];
#pragma unroll
    for (int k = 0; k < 7; ++k) {
        float2 t = __half22float2(yh[k]);
        h[2 * k]     = fmaxf(t.x, 0.f);
        h[2 * k + 1] = fmaxf(t.y, 0.f);
    }
    float o[H];
#pragma unroll
    for (int j = 0; j < H; ++j) {
        float a = 0.f;
#pragma unroll
        for (int i = 0; i < H; ++i) a = fmaf(h[i], w[i * H + j], a);
        o[j] = a;
    }
    __half2 ov[HP2];
#pragma unroll
    for (int j = 0; j < 7; ++j) ov[j] = __floats2half2_rn(o[2 * j], o[2 * j + 1]);
    ov[7] = __floats2half2_rn(0.f, 0.f);
    float4* dst = reinterpret_cast<float4*>(HW + (size_t)n * HP2);
    dst[0] = *reinterpret_cast<float4*>(&ov[0]);
    dst[1] = *reinterpret_cast<float4*>(&ov[4]);
}

// ---------------- Fused tail with LDS-staged coalesced output --------------
__global__ __launch_bounds__(256) void final_kernel(
        const __half2* __restrict__ Y2,
        const float* __restrict__ Wd1,
        const float* __restrict__ bd1,
        const float* __restrict__ Wd2,
        const float* __restrict__ bd2,
        float* __restrict__ out, int N) {
    __shared__ float wd1[H * H], wd2[H * P], b1[H], b2[P];
    __shared__ float so[256 * OUTW];   // 30 KB staging
    for (int i = threadIdx.x; i < H * H; i += 256) wd1[i] = Wd1[i];
    for (int i = threadIdx.x; i < H * P; i += 256) wd2[i] = Wd2[i];
    if (threadIdx.x < H) b1[threadIdx.x] = bd1[threadIdx.x];
    if (threadIdx.x < P) b2[threadIdx.x] = bd2[threadIdx.x];
    __syncthreads();

    int base = blockIdx.x * 256;
    int n = base + threadIdx.x;
    if (n < N) {
        const float4* yr4 = reinterpret_cast<const float4*>(Y2 + (size_t)n * HP2);
        float4 ya = yr4[0], yb = yr4[1];
        __half2 yh[HP2];
        *reinterpret_cast<float4*>(&yh[0]) = ya;
        *reinterpret_cast<float4*>(&yh[4]) = yb;
        float h[H];
#pragma unroll
        for (int k = 0; k < 7; ++k) {
            float2 t = __half22float2(yh[k]);
            h[2 * k]     = fmaxf(t.x, 0.f);
            h[2 * k + 1] = fmaxf(t.y, 0.f);
        }
        float* so_row = &so[threadIdx.x * OUTW];
        float pd7[LATc];
#pragma unroll
        for (int j = 0; j < H; ++j) {
            float a = b1[j];
#pragma unroll
            for (int i = 0; i < H; ++i) a = fmaf(h[i], wd1[i * H + j], a);
            float t = tanhf(a);
            if (j < LATc) so_row[j] = t;
            else pd7[j - LATc] = t;
        }
#pragma unroll
        for (int k = 0; k < LATc; ++k) {
            float x = pd7[k] + SP_INV_1;
            so_row[LATc + k] = log1pf(expf(x));   // softplus
        }
#pragma unroll
        for (int j = 0; j < P; ++j) {
            float a = b2[j];
#pragma unroll
            for (int i = 0; i < H; ++i) a = fmaf(h[i], wd2[i * P + j], a);
            so_row[14 + j] = tanhf(a);
        }
    }
    __syncthreads();

    int rowsHere = N - base;
    if (rowsHere > 256) rowsHere = 256;
    if (rowsHere < 0) rowsHere = 0;
    int cnt = rowsHere * OUTW;
    float* obase = out + (size_t)base * OUTW;
    for (int i = threadIdx.x; i < cnt; i += 256) obase[i] = so[i];
}

extern "C" void kernel_launch(void* const* d_in, const int* in_sizes, int n_in,
                              void* d_out, int out_size, void* d_ws, size_t ws_size,
                              hipStream_t stream) {
    const float* X    = (const float*)d_in[0];
    const int*   rows = (const int*)d_in[1];
    const int*   cols = (const int*)d_in[2];
    const float* vals = (const float*)d_in[3];
    const float* W1   = (const float*)d_in[4];
    const float* W2   = (const float*)d_in[5];
    const float* Wd1  = (const float*)d_in[6];
    const float* bd1  = (const float*)d_in[7];
    const float* Wd2  = (const float*)d_in[8];
    const float* bd2  = (const float*)d_in[9];
    float* out = (float*)d_out;

    const int N = in_sizes[0] / D;   // 100000
    const int E = in_sizes[1];       // 1000000

    // workspace (half2 rows, 32B/node): XW | HW | Y1 | Y2
    __half2* XW = (__half2*)d_ws;
    __half2* HW = XW + (size_t)N * HP2;
    __half2* Y1 = HW + (size_t)N * HP2;
    __half2* Y2 = Y1 + (size_t)N * HP2;

    int blkN  = (N + 255) / 256;
    int blkN2 = (2 * N + 255) / 256;          // 2 threads per node
    long long spmmThreads = (long long)E * 8;
    unsigned blkS = (unsigned)((spmmThreads + 255) / 256);

    dense_xw_kernel<<<blkN2, 256, 0, stream>>>(X, W1, XW, Y1, Y2, N);
    spmm_pk_kernel<<<blkS, 256, 0, stream>>>(XW, rows, cols, vals, Y1, E);
    dense_hw_kernel<<<blkN, 256, 0, stream>>>(Y1, W2, HW, N);
    spmm_pk_kernel<<<blkS, 256, 0, stream>>>(HW, rows, cols, vals, Y2, E);
    final_kernel<<<blkN, 256, 0, stream>>>(Y2, Wd1, bd1, Wd2, bd2, out, N);
}